// Round 1
// baseline (449.340 us; speedup 1.0000x reference)
//
#include <hip/hip_runtime.h>
#include <hip/hip_bf16.h>

// ---------------------------------------------------------------------------
// SimpleSelfAttention: out = softmax((xWq^T+bq)(xWk^T+bk)^T / 32) (xWv^T+bv)
// B=4, S=2048, E=1024, fp32 in/out. Internally bf16 MFMA with fp32 accum.
// ws layout (64 MB needed): Q@0 (16MB), K@16MB, S/P@32MB (32MB).
//   V reuses Q's region (after scores GEMM); VT reuses K's region.
// ---------------------------------------------------------------------------

typedef __attribute__((ext_vector_type(8))) short bf16x8;
typedef __attribute__((ext_vector_type(4))) short bf16x4;
typedef __attribute__((ext_vector_type(4))) float f32x4;

#define DEVI static __device__ __forceinline__

DEVI short to_bf16(float f) {
    unsigned u = __builtin_bit_cast(unsigned, f);
    u += 0x7fffu + ((u >> 16) & 1u);          // RNE (inputs are finite/normal)
    return (short)(u >> 16);
}
DEVI float from_bf16(short s) {
    return __builtin_bit_cast(float, (unsigned)((unsigned short)s) << 16);
}

// Stage a 128x32 tile (K-major source) into LDS [128][40] (pad -> <=2-way bank conflicts).
// fp32 sources are converted to bf16 on the fly.
template<typename T>
DEVI void stage_tile(short (*dst)[40], const T* __restrict__ src, long ld, int k0, int tid) {
    if constexpr (sizeof(T) == 4) {
        #pragma unroll
        for (int i = 0; i < 4; ++i) {
            int q = tid + 256 * i;          // 1024 float4 loads
            int row = q >> 3, kk = (q & 7) * 4;
            float4 v = *(const float4*)&src[(long)row * ld + k0 + kk];
            bf16x4 s = { to_bf16(v.x), to_bf16(v.y), to_bf16(v.z), to_bf16(v.w) };
            *(bf16x4*)&dst[row][kk] = s;    // 8B aligned (row*80 + 8*(q&7))
        }
    } else {
        #pragma unroll
        for (int i = 0; i < 2; ++i) {
            int q = tid + 256 * i;          // 512 16B loads
            int row = q >> 2, kk = (q & 3) * 8;
            *(bf16x8*)&dst[row][kk] = *(const bf16x8*)&src[(long)row * ld + k0 + kk];
        }
    }
}

// C[z][M][N] = scale * A[z][M][K] . B[z][N][K]^T (+ bias[N])
// Both operands K-major (contiguous K). 128x128 tile, 4 waves, 16x16x32 bf16 MFMA.
template<typename TA, typename TB, bool BIAS, typename TOUT>
__global__ __launch_bounds__(256, 2)
void gemm_tn(const TA* __restrict__ A, long lda, long bsA,
             const TB* __restrict__ B, long ldb, long bsB,
             const float* __restrict__ bias,
             TOUT* __restrict__ C, long ldc, long bsC,
             int K, float scale)
{
    __shared__ __align__(16) short As[128][40];
    __shared__ __align__(16) short Bs[128][40];

    const int tid = threadIdx.x;
    const int z = blockIdx.z;
    const long m0 = (long)blockIdx.y * 128;
    const long n0 = (long)blockIdx.x * 128;
    const TA* Ab = A + (long)z * bsA + m0 * lda;
    const TB* Bb = B + (long)z * bsB + n0 * ldb;

    const int wave = tid >> 6;
    const int lane = tid & 63;
    const int wr = (wave >> 1) * 64;     // wave's 64x64 sub-tile
    const int wc = (wave & 1) * 64;
    const int lrow = lane & 15;
    const int kgrp = (lane >> 4) * 8;    // 8 contiguous k per lane-group; same
                                         // permutation on A and B => correct sum.

    f32x4 acc[4][4] = {};

    for (int k0 = 0; k0 < K; k0 += 32) {
        stage_tile(As, Ab, lda, k0, tid);
        stage_tile(Bs, Bb, ldb, k0, tid);
        __syncthreads();

        bf16x8 af[4], bfr[4];
        #pragma unroll
        for (int m = 0; m < 4; ++m)
            af[m] = *(const bf16x8*)&As[wr + m * 16 + lrow][kgrp];
        #pragma unroll
        for (int n = 0; n < 4; ++n)
            bfr[n] = *(const bf16x8*)&Bs[wc + n * 16 + lrow][kgrp];

        #pragma unroll
        for (int m = 0; m < 4; ++m) {
            #pragma unroll
            for (int n = 0; n < 4; ++n)
                acc[m][n] = __builtin_amdgcn_mfma_f32_16x16x32_bf16(
                    af[m], bfr[n], acc[m][n], 0, 0, 0);
        }
        __syncthreads();
    }

    // C/D layout (verified m89): col = lane&15, row = (lane>>4)*4 + reg
    TOUT* Cb = C + (long)z * bsC + m0 * ldc + n0;
    #pragma unroll
    for (int m = 0; m < 4; ++m) {
        #pragma unroll
        for (int n = 0; n < 4; ++n) {
            #pragma unroll
            for (int r = 0; r < 4; ++r) {
                int row = wr + m * 16 + (lane >> 4) * 4 + r;
                int col = wc + n * 16 + lrow;
                float v = acc[m][n][r] * scale;
                if constexpr (BIAS) v += bias[n0 + col];
                if constexpr (sizeof(TOUT) == 2)
                    Cb[(long)row * ldc + col] = to_bf16(v);
                else
                    Cb[(long)row * ldc + col] = v;
            }
        }
    }
}

// In-place row softmax over bf16 rows of length ncols (=2048). One block/row.
__global__ __launch_bounds__(256)
void softmax_rows(short* __restrict__ S, int ncols)
{
    const long row = blockIdx.x;
    short* p = S + row * (long)ncols;
    const int t = threadIdx.x;

    union { bf16x8 v; short s[8]; } u;
    u.v = *(const bf16x8*)&p[t * 8];
    float f[8];
    float m = -3.0e38f;
    #pragma unroll
    for (int j = 0; j < 8; ++j) { f[j] = from_bf16(u.s[j]); m = fmaxf(m, f[j]); }
    #pragma unroll
    for (int off = 32; off > 0; off >>= 1) m = fmaxf(m, __shfl_xor(m, off));

    __shared__ float red[8];
    const int wave = t >> 6;
    if ((t & 63) == 0) red[wave] = m;
    __syncthreads();
    m = fmaxf(fmaxf(red[0], red[1]), fmaxf(red[2], red[3]));

    float sum = 0.f;
    #pragma unroll
    for (int j = 0; j < 8; ++j) { f[j] = __expf(f[j] - m); sum += f[j]; }
    #pragma unroll
    for (int off = 32; off > 0; off >>= 1) sum += __shfl_xor(sum, off);
    if ((t & 63) == 0) red[4 + wave] = sum;
    __syncthreads();
    sum = red[4] + red[5] + red[6] + red[7];

    const float inv = 1.0f / sum;
    #pragma unroll
    for (int j = 0; j < 8; ++j) u.s[j] = to_bf16(f[j] * inv);
    *(bf16x8*)&p[t * 8] = u.v;
}

// dst[z][c][r] = src[z][r][c], bf16, 32x32 LDS tiles (pad 33 -> conflict-light).
__global__ __launch_bounds__(256)
void transpose_bf16(const short* __restrict__ src, short* __restrict__ dst, int R, int Cc)
{
    __shared__ short tl[32][33];
    const long zoff = (long)blockIdx.z * R * Cc;
    const int r0 = blockIdx.x * 32;
    const int c0 = blockIdx.y * 32;
    const int tid = threadIdx.x;
    #pragma unroll
    for (int i = 0; i < 4; ++i) {
        int q = tid + 256 * i;
        int r = q >> 5, c = q & 31;
        tl[r][c] = src[zoff + (long)(r0 + r) * Cc + c0 + c];
    }
    __syncthreads();
    #pragma unroll
    for (int i = 0; i < 4; ++i) {
        int q = tid + 256 * i;
        int r = q >> 5, c = q & 31;
        dst[zoff + (long)(c0 + r) * R + r0 + c] = tl[c][r];
    }
}

extern "C" void kernel_launch(void* const* d_in, const int* in_sizes, int n_in,
                              void* d_out, int out_size, void* d_ws, size_t ws_size,
                              hipStream_t stream)
{
    (void)in_sizes; (void)n_in; (void)out_size; (void)ws_size;

    const float* x  = (const float*)d_in[0];
    const float* Wq = (const float*)d_in[1];
    const float* bq = (const float*)d_in[2];
    const float* Wk = (const float*)d_in[3];
    const float* bk = (const float*)d_in[4];
    const float* Wv = (const float*)d_in[5];
    const float* bv = (const float*)d_in[6];
    float* out = (float*)d_out;

    const int Bz = 4, S = 2048, E = 1024;
    const long MB16 = 16l * 1024 * 1024;
    char* w = (char*)d_ws;
    short* Q  = (short*)(w);              // [8192][1024] bf16
    short* Kb = (short*)(w + MB16);       // [8192][1024] bf16
    short* P  = (short*)(w + 2 * MB16);   // [4][2048][2048] bf16 (scores then attn)
    short* V  = (short*)(w);              // reuses Q region
    short* VT = (short*)(w + MB16);       // reuses K region

    dim3 blk(256);

    // Q = x Wq^T + bq ; K = x Wk^T + bk   (M=8192, N=1024, K=1024)
    gemm_tn<float, float, true, short><<<dim3(8, 64, 1), blk, 0, stream>>>(
        x, E, 0, Wq, E, 0, bq, Q, E, 0, E, 1.0f);
    gemm_tn<float, float, true, short><<<dim3(8, 64, 1), blk, 0, stream>>>(
        x, E, 0, Wk, E, 0, bk, Kb, E, 0, E, 1.0f);

    // S[b] = Q[b] K[b]^T / 32   (per batch M=N=2048, K=1024)
    gemm_tn<short, short, false, short><<<dim3(16, 16, Bz), blk, 0, stream>>>(
        Q, E, (long)S * E, Kb, E, (long)S * E, nullptr,
        P, S, (long)S * S, E, 0.03125f);

    // softmax rows in place
    softmax_rows<<<dim3(Bz * S), blk, 0, stream>>>(P, S);

    // V = x Wv^T + bv  (into Q's region, now free)
    gemm_tn<float, float, true, short><<<dim3(8, 64, 1), blk, 0, stream>>>(
        x, E, 0, Wv, E, 0, bv, V, E, 0, E, 1.0f);

    // VT[b] = V[b]^T  ([1024][2048], into K's region)
    transpose_bf16<<<dim3(S / 32, E / 32, Bz), blk, 0, stream>>>(V, VT, S, E);

    // out[b] = P[b] V[b]  (M=2048, N=1024, K=2048; B operand = VT, K-major)
    gemm_tn<short, short, false, float><<<dim3(8, 16, Bz), blk, 0, stream>>>(
        P, S, (long)S * S, VT, S, (long)E * S, nullptr,
        out, E, (long)S * E, S, 1.0f);
}

// Round 2
// 417.179 us; speedup vs baseline: 1.0771x; 1.0771x over previous
//
#include <hip/hip_runtime.h>
#include <hip/hip_bf16.h>

// ---------------------------------------------------------------------------
// SimpleSelfAttention: out = softmax((xWq^T+bq)(xWk^T+bk)^T / 32) (xWv^T+bv)
// B=4, S=2048, E=1024, fp32 in/out. Internally bf16 MFMA, fp32 accum.
//
// Pipeline (all bf16 GEMMs, m97-style 128x128 tile + global_load_lds +
// XOR-swizzled LDS via pre-swizzled global source):
//   1. cvt x->xb, Wq/Wk/Wv->bf16
//   2. Q = xb Wq^T + bq ; K = xb Wk^T + bk        (row-major [8192][1024])
//   3. per batch b: S_b = Q_b K_b^T /32 -> P ; softmax(P) ;
//                   VT_b = Wv xb_b^T + bv (row bias) ; out_b = P VT_b^T
//
// ws layout (shorts), 62MB total:
//   xb @0 (8M) | Wqb @8M | Wkb @9M | Wvb @10M | Q @11M | K @19M | P @27M (4M)
//   VT @8M (2M, reuses dead Wqb/Wkb after projections)
// ---------------------------------------------------------------------------

typedef __attribute__((ext_vector_type(8))) short bf16x8;
typedef __attribute__((ext_vector_type(4))) float f32x4;

#define DEVI static __device__ __forceinline__

DEVI short to_bf16(float f) {
    unsigned u = __builtin_bit_cast(unsigned, f);
    u += 0x7fffu + ((u >> 16) & 1u);          // RNE (finite/normal inputs)
    return (short)(u >> 16);
}
DEVI float from_bf16(short s) {
    return __builtin_bit_cast(float, (unsigned)((unsigned short)s) << 16);
}

DEVI void gload_lds16(const short* g, short* l) {
    __builtin_amdgcn_global_load_lds(
        (const __attribute__((address_space(1))) void*)g,
        (__attribute__((address_space(3))) void*)l, 16, 0, 0);
}

// C[M][N] = scale * A[M][K] . B[N][K]^T (+ bias)
// A,B bf16 K-major. 128x128 tile, BK=64, 4 waves, 16x16x32 bf16 MFMA.
// LDS: linear dest for global_load_lds; 16B chunk c of row r holds logical
// chunk c^(r&7) (source pre-swizzled), ds_read applies the same XOR.
// BIAS: 0=none, 1=col bias[n], 2=row bias[m].
template<int BIAS, typename TOUT>
__global__ __launch_bounds__(256)
void gemm_tn(const short* __restrict__ A, long lda,
             const short* __restrict__ B, long ldb,
             const float* __restrict__ bias,
             TOUT* __restrict__ C, long ldc,
             int K, float scale)
{
    __shared__ __align__(16) short As[128 * 64];
    __shared__ __align__(16) short Bs[128 * 64];

    const int tid = threadIdx.x;
    const long m0 = (long)blockIdx.y * 128;
    const long n0 = (long)blockIdx.x * 128;
    const short* Ab = A + m0 * lda;
    const short* Bb = B + n0 * ldb;

    const int wave = tid >> 6;
    const int lane = tid & 63;
    const int wr = (wave >> 1) * 64;     // wave's 64x64 sub-tile
    const int wc = (wave & 1) * 64;
    const int lrow = lane & 15;
    const int lq = lane >> 4;            // quarter-wave = logical k-chunk base

    // staging: thread covers LDS 16B-chunk t = i*256+tid; row=t>>3, c'=t&7.
    // data there must be logical chunk c'^(row&7).
    int srow[4], scol[4];
    #pragma unroll
    for (int i = 0; i < 4; ++i) {
        int t = i * 256 + tid;
        srow[i] = t >> 3;
        scol[i] = ((t & 7) ^ (srow[i] & 7)) * 8;
    }

    f32x4 acc[4][4] = {};

    for (int k0 = 0; k0 < K; k0 += 64) {
        #pragma unroll
        for (int i = 0; i < 4; ++i)
            gload_lds16(Ab + (long)srow[i] * lda + k0 + scol[i],
                        &As[(i * 256 + tid) * 8]);
        #pragma unroll
        for (int i = 0; i < 4; ++i)
            gload_lds16(Bb + (long)srow[i] * ldb + k0 + scol[i],
                        &Bs[(i * 256 + tid) * 8]);
        __syncthreads();

        #pragma unroll
        for (int kk = 0; kk < 2; ++kk) {
            bf16x8 af[4], bfr[4];
            #pragma unroll
            for (int m = 0; m < 4; ++m) {
                int row = wr + m * 16 + lrow;
                int c = (lq + kk * 4) ^ (row & 7);
                af[m] = *(const bf16x8*)&As[row * 64 + c * 8];
            }
            #pragma unroll
            for (int n = 0; n < 4; ++n) {
                int row = wc + n * 16 + lrow;
                int c = (lq + kk * 4) ^ (row & 7);
                bfr[n] = *(const bf16x8*)&Bs[row * 64 + c * 8];
            }
            #pragma unroll
            for (int m = 0; m < 4; ++m)
                #pragma unroll
                for (int n = 0; n < 4; ++n)
                    acc[m][n] = __builtin_amdgcn_mfma_f32_16x16x32_bf16(
                        af[m], bfr[n], acc[m][n], 0, 0, 0);
        }
        __syncthreads();
    }

    // C/D layout (verified m89): col = lane&15, row = (lane>>4)*4 + reg
    TOUT* Cb = C + m0 * ldc + n0;
    #pragma unroll
    for (int m = 0; m < 4; ++m) {
        #pragma unroll
        for (int n = 0; n < 4; ++n) {
            #pragma unroll
            for (int r = 0; r < 4; ++r) {
                int row = wr + m * 16 + (lane >> 4) * 4 + r;
                int col = wc + n * 16 + lrow;
                float v = acc[m][n][r] * scale;
                if constexpr (BIAS == 1) v += bias[n0 + col];
                if constexpr (BIAS == 2) v += bias[m0 + row];
                if constexpr (sizeof(TOUT) == 2)
                    Cb[(long)row * ldc + col] = to_bf16(v);
                else
                    Cb[(long)row * ldc + col] = v;
            }
        }
    }
}

// fp32 -> bf16, 8 elems/thread
__global__ __launch_bounds__(256)
void cvt_f32_bf16(const float* __restrict__ src, short* __restrict__ dst, int n8)
{
    int i = blockIdx.x * 256 + threadIdx.x;
    if (i < n8) {
        float4 a = ((const float4*)src)[2 * i];
        float4 b = ((const float4*)src)[2 * i + 1];
        bf16x8 o = { to_bf16(a.x), to_bf16(a.y), to_bf16(a.z), to_bf16(a.w),
                     to_bf16(b.x), to_bf16(b.y), to_bf16(b.z), to_bf16(b.w) };
        *(bf16x8*)&dst[i * 8] = o;
    }
}

// In-place row softmax over bf16 rows of length 2048. One block/row.
__global__ __launch_bounds__(256)
void softmax_rows(short* __restrict__ S, int ncols)
{
    const long row = blockIdx.x;
    short* p = S + row * (long)ncols;
    const int t = threadIdx.x;

    union { bf16x8 v; short s[8]; } u;
    u.v = *(const bf16x8*)&p[t * 8];
    float f[8];
    float m = -3.0e38f;
    #pragma unroll
    for (int j = 0; j < 8; ++j) { f[j] = from_bf16(u.s[j]); m = fmaxf(m, f[j]); }
    #pragma unroll
    for (int off = 32; off > 0; off >>= 1) m = fmaxf(m, __shfl_xor(m, off));

    __shared__ float red[8];
    const int wave = t >> 6;
    if ((t & 63) == 0) red[wave] = m;
    __syncthreads();
    m = fmaxf(fmaxf(red[0], red[1]), fmaxf(red[2], red[3]));

    float sum = 0.f;
    #pragma unroll
    for (int j = 0; j < 8; ++j) { f[j] = __expf(f[j] - m); sum += f[j]; }
    #pragma unroll
    for (int off = 32; off > 0; off >>= 1) sum += __shfl_xor(sum, off);
    if ((t & 63) == 0) red[4 + wave] = sum;
    __syncthreads();
    sum = red[4] + red[5] + red[6] + red[7];

    const float inv = 1.0f / sum;
    #pragma unroll
    for (int j = 0; j < 8; ++j) u.s[j] = to_bf16(f[j] * inv);
    *(bf16x8*)&p[t * 8] = u.v;
}

extern "C" void kernel_launch(void* const* d_in, const int* in_sizes, int n_in,
                              void* d_out, int out_size, void* d_ws, size_t ws_size,
                              hipStream_t stream)
{
    (void)in_sizes; (void)n_in; (void)out_size; (void)ws_size;

    const float* x  = (const float*)d_in[0];
    const float* Wq = (const float*)d_in[1];
    const float* bq = (const float*)d_in[2];
    const float* Wk = (const float*)d_in[3];
    const float* bk = (const float*)d_in[4];
    const float* Wv = (const float*)d_in[5];
    const float* bv = (const float*)d_in[6];
    float* out = (float*)d_out;

    const int Bz = 4, S = 2048, E = 1024;
    const long M1 = 1024l * 1024;
    short* w   = (short*)d_ws;
    short* xb  = w;                 // [8192][1024]
    short* Wqb = w + 8 * M1;        // [1024][1024]
    short* Wkb = w + 9 * M1;
    short* Wvb = w + 10 * M1;
    short* Q   = w + 11 * M1;       // [8192][1024]
    short* Kb  = w + 19 * M1;       // [8192][1024]
    short* P   = w + 27 * M1;       // [2048][2048] per-batch scores/attn
    short* VT  = w + 8 * M1;        // [1024][2048] per-batch, over Wqb/Wkb

    dim3 blk(256);

    cvt_f32_bf16<<<dim3(4096), blk, 0, stream>>>(x, xb, (int)M1);
    cvt_f32_bf16<<<dim3(512), blk, 0, stream>>>(Wq, Wqb, (int)(M1 / 8));
    cvt_f32_bf16<<<dim3(512), blk, 0, stream>>>(Wk, Wkb, (int)(M1 / 8));
    cvt_f32_bf16<<<dim3(512), blk, 0, stream>>>(Wv, Wvb, (int)(M1 / 8));

    // Q = xb Wq^T + bq ; K = xb Wk^T + bk   (M=8192, N=1024, K=1024)
    gemm_tn<1, short><<<dim3(8, 64), blk, 0, stream>>>(
        xb, E, Wqb, E, bq, Q, E, E, 1.0f);
    gemm_tn<1, short><<<dim3(8, 64), blk, 0, stream>>>(
        xb, E, Wkb, E, bk, Kb, E, E, 1.0f);

    for (int b = 0; b < Bz; ++b) {
        const short* Qb  = Q + (long)b * S * E;
        const short* Kbb = Kb + (long)b * S * E;
        const short* xbb = xb + (long)b * S * E;
        float* outb = out + (long)b * S * E;

        // S_b = Q_b K_b^T / 32   (M=N=2048, K=1024)
        gemm_tn<0, short><<<dim3(16, 16), blk, 0, stream>>>(
            Qb, E, Kbb, E, nullptr, P, S, E, 0.03125f);

        softmax_rows<<<dim3(S), blk, 0, stream>>>(P, S);

        // VT_b = Wv xb_b^T + bv (row bias)   (M=1024, N=2048, K=1024)
        gemm_tn<2, short><<<dim3(16, 8), blk, 0, stream>>>(
            Wvb, E, xbb, E, bv, VT, S, E, 1.0f);

        // out_b = P VT_b^T   (M=2048, N=1024, K=2048), fp32 out
        gemm_tn<0, float><<<dim3(8, 16), blk, 0, stream>>>(
            P, S, VT, S, nullptr, outb, E, S, 1.0f);
    }
}

// Round 3
// 221.169 us; speedup vs baseline: 2.0317x; 1.8862x over previous
//
#include <hip/hip_runtime.h>
#include <hip/hip_bf16.h>

// ---------------------------------------------------------------------------
// SimpleSelfAttention: out = softmax((xWq^T+bq)(xWk^T+bk)^T / 32) (xWv^T+bv)
// B=4, S=2048, E=1024, fp32 in/out. Internally bf16 MFMA, fp32 accum.
//
// Fully z-batched pipeline (no host loop):
//   1. cvt x->xb, W*->bf16           (xb, W live in d_out as scratch)
//   2. QKV = one gemm launch, z in {0,1,2} selects W/bias/output
//   3. transpose V -> VT (VT overwrites dead xb in d_out)
//   4. scores (z=0..3) -> P ; softmax ; out = P VT^T -> ws ; d2d copy -> d_out
//
// ws (32M shorts = 64MB): Q@0 | K@8M | P@16M (32MB; V@16M lives here pre-scores)
//   PV writes fp32 out over dead Q+K (ws bytes 0..32MB), then copied to d_out.
// d_out scratch (32MB): xb@0 (16MB) | Wb@16MB (6MB) ; later VT@0 (16MB).
// ---------------------------------------------------------------------------

typedef __attribute__((ext_vector_type(8))) short bf16x8;
typedef __attribute__((ext_vector_type(4))) float f32x4;

#define DEVI static __device__ __forceinline__

DEVI short to_bf16(float f) {
    unsigned u = __builtin_bit_cast(unsigned, f);
    u += 0x7fffu + ((u >> 16) & 1u);          // RNE (finite/normal inputs)
    return (short)(u >> 16);
}
DEVI float from_bf16(short s) {
    return __builtin_bit_cast(float, (unsigned)((unsigned short)s) << 16);
}

DEVI void gload_lds16(const short* g, short* l) {
    __builtin_amdgcn_global_load_lds(
        (const __attribute__((address_space(1))) void*)g,
        (__attribute__((address_space(3))) void*)l, 16, 0, 0);
}

// C[z][M][N] = scale * A[z] . B[z]^T (+ bias_z[n])
// A,B bf16 K-major. 128x128 tile, BK=64, 4 waves, 16x16x32 bf16 MFMA.
// LDS: linear dest for global_load_lds; 16B chunk c of row r holds logical
// chunk c^(r&7) (source pre-swizzled), ds_read applies the same XOR.
// BIAS: 0=none, 1=col bias selected by z from {b0,b1,b2}.
template<int BIAS, typename TOUT>
__global__ __launch_bounds__(256)
void gemm_tn(const short* __restrict__ A, long lda, long bsA,
             const short* __restrict__ B, long ldb, long bsB,
             const float* __restrict__ b0, const float* __restrict__ b1,
             const float* __restrict__ b2,
             TOUT* __restrict__ C, long ldc, long bsC,
             int K, float scale)
{
    __shared__ __align__(16) short As[128 * 64];
    __shared__ __align__(16) short Bs[128 * 64];

    const int tid = threadIdx.x;
    const int z = blockIdx.z;
    const long m0 = (long)blockIdx.y * 128;
    const long n0 = (long)blockIdx.x * 128;
    const short* Ab = A + (long)z * bsA + m0 * lda;
    const short* Bb = B + (long)z * bsB + n0 * ldb;
    const float* bias = (z == 0) ? b0 : (z == 1) ? b1 : b2;

    const int wave = tid >> 6;
    const int lane = tid & 63;
    const int wr = (wave >> 1) * 64;     // wave's 64x64 sub-tile
    const int wc = (wave & 1) * 64;
    const int lrow = lane & 15;
    const int lq = lane >> 4;            // quarter-wave = logical k-chunk base

    // staging: thread covers LDS 16B-chunk t = i*256+tid; row=t>>3, c'=t&7.
    // data there must be logical chunk c'^(row&7).
    int srow[4], scol[4];
    #pragma unroll
    for (int i = 0; i < 4; ++i) {
        int t = i * 256 + tid;
        srow[i] = t >> 3;
        scol[i] = ((t & 7) ^ (srow[i] & 7)) * 8;
    }

    f32x4 acc[4][4] = {};

    for (int k0 = 0; k0 < K; k0 += 64) {
        #pragma unroll
        for (int i = 0; i < 4; ++i)
            gload_lds16(Ab + (long)srow[i] * lda + k0 + scol[i],
                        &As[(i * 256 + tid) * 8]);
        #pragma unroll
        for (int i = 0; i < 4; ++i)
            gload_lds16(Bb + (long)srow[i] * ldb + k0 + scol[i],
                        &Bs[(i * 256 + tid) * 8]);
        __syncthreads();

        #pragma unroll
        for (int kk = 0; kk < 2; ++kk) {
            bf16x8 af[4], bfr[4];
            #pragma unroll
            for (int m = 0; m < 4; ++m) {
                int row = wr + m * 16 + lrow;
                int c = (lq + kk * 4) ^ (row & 7);
                af[m] = *(const bf16x8*)&As[row * 64 + c * 8];
            }
            #pragma unroll
            for (int n = 0; n < 4; ++n) {
                int row = wc + n * 16 + lrow;
                int c = (lq + kk * 4) ^ (row & 7);
                bfr[n] = *(const bf16x8*)&Bs[row * 64 + c * 8];
            }
            #pragma unroll
            for (int m = 0; m < 4; ++m)
                #pragma unroll
                for (int n = 0; n < 4; ++n)
                    acc[m][n] = __builtin_amdgcn_mfma_f32_16x16x32_bf16(
                        af[m], bfr[n], acc[m][n], 0, 0, 0);
        }
        __syncthreads();
    }

    // C/D layout (verified m89): col = lane&15, row = (lane>>4)*4 + reg
    TOUT* Cb = C + (long)z * bsC + m0 * ldc + n0;
    #pragma unroll
    for (int m = 0; m < 4; ++m) {
        #pragma unroll
        for (int n = 0; n < 4; ++n) {
            #pragma unroll
            for (int r = 0; r < 4; ++r) {
                int row = wr + m * 16 + (lane >> 4) * 4 + r;
                int col = wc + n * 16 + lrow;
                float v = acc[m][n][r] * scale;
                if constexpr (BIAS == 1) v += bias[n0 + col];
                if constexpr (sizeof(TOUT) == 2)
                    Cb[(long)row * ldc + col] = to_bf16(v);
                else
                    Cb[(long)row * ldc + col] = v;
            }
        }
    }
}

// fp32 -> bf16, 8 elems/thread
__global__ __launch_bounds__(256)
void cvt_f32_bf16(const float* __restrict__ src, short* __restrict__ dst, int n8)
{
    int i = blockIdx.x * 256 + threadIdx.x;
    if (i < n8) {
        float4 a = ((const float4*)src)[2 * i];
        float4 b = ((const float4*)src)[2 * i + 1];
        bf16x8 o = { to_bf16(a.x), to_bf16(a.y), to_bf16(a.z), to_bf16(a.w),
                     to_bf16(b.x), to_bf16(b.y), to_bf16(b.z), to_bf16(b.w) };
        *(bf16x8*)&dst[i * 8] = o;
    }
}

// In-place row softmax over bf16 rows of length 2048. One block/row.
__global__ __launch_bounds__(256)
void softmax_rows(short* __restrict__ S, int ncols)
{
    const long row = blockIdx.x;
    short* p = S + row * (long)ncols;
    const int t = threadIdx.x;

    union { bf16x8 v; short s[8]; } u;
    u.v = *(const bf16x8*)&p[t * 8];
    float f[8];
    float m = -3.0e38f;
    #pragma unroll
    for (int j = 0; j < 8; ++j) { f[j] = from_bf16(u.s[j]); m = fmaxf(m, f[j]); }
    #pragma unroll
    for (int off = 32; off > 0; off >>= 1) m = fmaxf(m, __shfl_xor(m, off));

    __shared__ float red[8];
    const int wave = t >> 6;
    if ((t & 63) == 0) red[wave] = m;
    __syncthreads();
    m = fmaxf(fmaxf(red[0], red[1]), fmaxf(red[2], red[3]));

    float sum = 0.f;
    #pragma unroll
    for (int j = 0; j < 8; ++j) { f[j] = __expf(f[j] - m); sum += f[j]; }
    #pragma unroll
    for (int off = 32; off > 0; off >>= 1) sum += __shfl_xor(sum, off);
    if ((t & 63) == 0) red[4 + wave] = sum;
    __syncthreads();
    sum = red[4] + red[5] + red[6] + red[7];

    const float inv = 1.0f / sum;
    #pragma unroll
    for (int j = 0; j < 8; ++j) u.s[j] = to_bf16(f[j] * inv);
    *(bf16x8*)&p[t * 8] = u.v;
}

// dst[z][c][r] = src[z][r][c], bf16, 32x32 LDS tiles.
__global__ __launch_bounds__(256)
void transpose_bf16(const short* __restrict__ src, short* __restrict__ dst, int R, int Cc)
{
    __shared__ short tl[32][33];
    const long zoff = (long)blockIdx.z * R * Cc;
    const int r0 = blockIdx.x * 32;
    const int c0 = blockIdx.y * 32;
    const int tid = threadIdx.x;
    #pragma unroll
    for (int i = 0; i < 4; ++i) {
        int q = tid + 256 * i;
        int r = q >> 5, c = q & 31;
        tl[r][c] = src[zoff + (long)(r0 + r) * Cc + c0 + c];
    }
    __syncthreads();
    #pragma unroll
    for (int i = 0; i < 4; ++i) {
        int q = tid + 256 * i;
        int r = q >> 5, c = q & 31;
        dst[zoff + (long)(c0 + r) * R + r0 + c] = tl[c][r];
    }
}

extern "C" void kernel_launch(void* const* d_in, const int* in_sizes, int n_in,
                              void* d_out, int out_size, void* d_ws, size_t ws_size,
                              hipStream_t stream)
{
    (void)in_sizes; (void)n_in; (void)out_size; (void)ws_size;

    const float* x  = (const float*)d_in[0];
    const float* Wq = (const float*)d_in[1];
    const float* bq = (const float*)d_in[2];
    const float* Wk = (const float*)d_in[3];
    const float* bk = (const float*)d_in[4];
    const float* Wv = (const float*)d_in[5];
    const float* bv = (const float*)d_in[6];

    const int S = 2048, E = 1024;
    const long M1 = 1024l * 1024;

    // ws regions (shorts)
    short* w  = (short*)d_ws;
    short* Q  = w;                  // [4][2048][1024]  (16MB)
    short* Kb = w + 8 * M1;         // [4][2048][1024]  (16MB)
    short* P  = w + 16 * M1;        // [4][2048][2048]  (32MB)
    short* V  = w + 16 * M1;        // [4][2048][1024] pre-scores, inside P region
    float* out_ws = (float*)w;      // [4][2048][1024] fp32 over dead Q+K (32MB)

    // d_out scratch regions
    short* dows = (short*)d_out;
    short* xb = dows;               // [8192][1024] bf16 (16MB)
    short* Wb = dows + 8 * M1;      // Wq,Wk,Wv bf16 (3 x 2MB)
    short* VT = dows;               // [4][1024][2048] bf16, over dead xb (16MB)

    dim3 blk(256);

    // 1. convert inputs to bf16
    cvt_f32_bf16<<<dim3(4096), blk, 0, stream>>>(x, xb, (int)M1);
    cvt_f32_bf16<<<dim3(512), blk, 0, stream>>>(Wq, Wb, (int)(M1 / 8));
    cvt_f32_bf16<<<dim3(512), blk, 0, stream>>>(Wk, Wb + M1, (int)(M1 / 8));
    cvt_f32_bf16<<<dim3(512), blk, 0, stream>>>(Wv, Wb + 2 * M1, (int)(M1 / 8));

    // 2. Q,K,V projections in one launch: z selects {Wq,bq,Q},{Wk,bk,K},{Wv,bv,V}
    //    M=8192, N=1024, K=1024; outputs contiguous (Q,K,V) with stride 8*M1.
    gemm_tn<1, short><<<dim3(8, 64, 3), blk, 0, stream>>>(
        xb, E, 0, Wb, E, M1, bq, bk, bv, Q, E, 8 * M1, E, 1.0f);

    // 3. VT[z] = V[z]^T  ([1024][2048]) into d_out (xb dead)
    transpose_bf16<<<dim3(S / 32, E / 32, 4), blk, 0, stream>>>(V, VT, S, E);

    // 4. scores: P[z] = Q[z] K[z]^T / 32  (M=N=2048, K=1024) — overwrites V
    gemm_tn<0, short><<<dim3(16, 16, 4), blk, 0, stream>>>(
        Q, E, 2 * M1, Kb, E, 2 * M1, nullptr, nullptr, nullptr,
        P, S, 4 * M1, E, 0.03125f);

    // 5. softmax rows in place
    softmax_rows<<<dim3(4 * S), blk, 0, stream>>>(P, S);

    // 6. out[z] = P[z] VT[z]^T  (M=2048, N=1024, K=2048) — fp32 into ws
    gemm_tn<0, float><<<dim3(8, 16, 4), blk, 0, stream>>>(
        P, S, 4 * M1, VT, S, 2 * M1, nullptr, nullptr, nullptr,
        out_ws, E, 2 * M1, S, 1.0f);

    // 7. copy result to d_out (overwrites VT scratch)
    hipMemcpyAsync(d_out, out_ws, 32l * 1024 * 1024,
                   hipMemcpyDeviceToDevice, stream);
}